// Round 5
// baseline (129.362 us; speedup 1.0000x reference)
//
#include <hip/hip_runtime.h>
#include <hip/hip_bf16.h>

// T=256, B=8, H1=512, U=64, H2=512, V=128
// Single-kernel producer/consumer design:
//   blocks  0-31 : W -> Wt (bf16, transposed)           -> flagW[i]
//   blocks 32-95 : pg[b,u,v] = g·W[512:]  (8 rows each) -> flagP[i]
//   blocks 96-607: consumer (b, 4 t-rows): pf MFMA + broadcast add + stream out
// Flags are write-once MAGIC; Wt/Pg are byte-identical every call, so
// steady-state pass-through reads are value-safe.
// R4 lesson: __builtin_nontemporal_store -> 0.5 TB/s uncached writes (10x). Plain stores.

typedef float  f32x4 __attribute__((ext_vector_type(4)));
typedef short  bh8   __attribute__((ext_vector_type(8)));

#define MAGIC 0x5bd1e995u

__device__ __forceinline__ unsigned short f2bf(float x) {
    unsigned u = __float_as_uint(x);
    return (unsigned short)((u + 0x7FFFu + ((u >> 16) & 1u)) >> 16);
}

__device__ __forceinline__ void waitFlags(const unsigned* f, int n) {
    const unsigned* p = f + ((threadIdx.x & 63) & (n - 1));
    for (;;) {
        unsigned v = __hip_atomic_load(p, __ATOMIC_RELAXED, __HIP_MEMORY_SCOPE_AGENT);
        if (__all(v == MAGIC)) break;
        __builtin_amdgcn_s_sleep(8);
    }
    __threadfence();                       // agent acquire
}

__device__ __forceinline__ void signalFlag(unsigned* f) {
    __syncthreads();                       // all block stores drained before barrier
    if (threadIdx.x == 0) {
        __threadfence();                   // agent release
        __hip_atomic_store(f, MAGIC, __ATOMIC_RELEASE, __HIP_MEMORY_SCOPE_AGENT);
    }
}

__global__ __launch_bounds__(256) void mega(const float* __restrict__ F,
                                            const float* __restrict__ G,
                                            const float* __restrict__ W,
                                            const float* __restrict__ bias,
                                            const int* __restrict__ f_lens,
                                            float* __restrict__ out,
                                            float* __restrict__ Pg,
                                            short* __restrict__ Wt,
                                            unsigned* __restrict__ flags,
                                            int lens_off) {
    __shared__ float sred[4][8][128];      // 16 KB (pg: [4][8][128], consumer: [4][4][128])

    const int tid = threadIdx.x;
    const int blk = blockIdx.x;
    unsigned* flagW = flags;
    unsigned* flagP = flags + 32;

    if (blk < 32) {
        // ---- W (1024x128 f32) -> Wt (128x1024 bf16) ----
        int gid = blk * 256 + tid;
        int v = gid & 127, h0 = (gid >> 7) * 16;
        short tmp[16];
#pragma unroll
        for (int i = 0; i < 16; ++i) tmp[i] = (short)f2bf(W[(h0 + i) * 128 + v]);
        bh8* dst = reinterpret_cast<bh8*>(Wt + v * 1024 + h0);
        dst[0] = *reinterpret_cast<bh8*>(&tmp[0]);
        dst[1] = *reinterpret_cast<bh8*>(&tmp[8]);
        signalFlag(&flagW[blk]);
        return;
    }

    if (blk < 96) {
        // ---- pg producer: 8 rows of Pg, wave-split-K, B gathered from raw W ----
        const int rowBase = (blk - 32) * 8;
        const int w = tid >> 6, lane = tid & 63, l15 = lane & 15, cc = lane >> 4;
        const float* arow = G + (rowBase + (l15 & 7)) * 512;

        f32x4 acc[8] = {};
#pragma unroll
        for (int kk = 0; kk < 4; ++kk) {
            const int k0 = w * 128 + kk * 32 + cc * 8;
            f32x4 a0 = *reinterpret_cast<const f32x4*>(arow + k0);
            f32x4 a1 = *reinterpret_cast<const f32x4*>(arow + k0 + 4);
            bh8 av;
            av[0] = (short)f2bf(a0[0]); av[1] = (short)f2bf(a0[1]);
            av[2] = (short)f2bf(a0[2]); av[3] = (short)f2bf(a0[3]);
            av[4] = (short)f2bf(a1[0]); av[5] = (short)f2bf(a1[1]);
            av[6] = (short)f2bf(a1[2]); av[7] = (short)f2bf(a1[3]);
#pragma unroll
            for (int j = 0; j < 8; ++j) {
                const float* wsrc = W + (512 + k0) * 128 + (j * 16 + l15);
                bh8 bv;
#pragma unroll
                for (int i = 0; i < 8; ++i) bv[i] = (short)f2bf(wsrc[i * 128]);
                acc[j] = __builtin_amdgcn_mfma_f32_16x16x32_bf16(av, bv, acc[j], 0, 0, 0);
            }
        }
        if (cc < 2) {                       // rows m = cc*4+q in [0,8); m>=8 duplicates
#pragma unroll
            for (int j = 0; j < 8; ++j)
#pragma unroll
                for (int q = 0; q < 4; ++q)
                    sred[w][cc * 4 + q][j * 16 + l15] = acc[j][q];
        }
        __syncthreads();
        const int row = tid >> 5, colq = tid & 31;
        f32x4 s = *reinterpret_cast<const f32x4*>(&sred[0][row][colq * 4]);
        s += *reinterpret_cast<const f32x4*>(&sred[1][row][colq * 4]);
        s += *reinterpret_cast<const f32x4*>(&sred[2][row][colq * 4]);
        s += *reinterpret_cast<const f32x4*>(&sred[3][row][colq * 4]);
        *reinterpret_cast<f32x4*>(Pg + (rowBase + row) * 128 + colq * 4) = s;
        signalFlag(&flagP[blk - 32]);
        return;
    }

    // ---- consumer: (b, 4 t-rows) ----
    const int cid = blk - 96;
    const int b = cid >> 6, t0 = (cid & 63) * 4;
    const int w = tid >> 6, lane = tid & 63, l15 = lane & 15, cc = lane >> 4;

    // prefetch + convert A fragments before waiting (f is [T][B][H1])
    const float* arow = F + ((t0 + (l15 & 3)) * 8 + b) * 512;
    bh8 av[4];
#pragma unroll
    for (int kk = 0; kk < 4; ++kk) {
        const int k0 = w * 128 + kk * 32 + cc * 8;
        f32x4 a0 = *reinterpret_cast<const f32x4*>(arow + k0);
        f32x4 a1 = *reinterpret_cast<const f32x4*>(arow + k0 + 4);
        av[kk][0] = (short)f2bf(a0[0]); av[kk][1] = (short)f2bf(a0[1]);
        av[kk][2] = (short)f2bf(a0[2]); av[kk][3] = (short)f2bf(a0[3]);
        av[kk][4] = (short)f2bf(a1[0]); av[kk][5] = (short)f2bf(a1[1]);
        av[kk][6] = (short)f2bf(a1[2]); av[kk][7] = (short)f2bf(a1[3]);
    }

    waitFlags(flagW, 32);

    f32x4 acc[8] = {};
#pragma unroll
    for (int kk = 0; kk < 4; ++kk) {
        const int k0 = w * 128 + kk * 32 + cc * 8;
#pragma unroll
        for (int j = 0; j < 8; ++j) {
            bh8 bv = *reinterpret_cast<const bh8*>(Wt + (j * 16 + l15) * 1024 + k0);
            acc[j] = __builtin_amdgcn_mfma_f32_16x16x32_bf16(av[kk], bv, acc[j], 0, 0, 0);
        }
    }
    if (cc == 0) {                          // rows m = q in [0,4); m>=4 duplicates
#pragma unroll
        for (int j = 0; j < 8; ++j)
#pragma unroll
            for (int q = 0; q < 4; ++q)
                sred[w][q][j * 16 + l15] = acc[j][q];
    }

    waitFlags(flagP, 64);
    __syncthreads();

    const int vq = tid & 31, ug = tid >> 5;
    const f32x4 bi = *reinterpret_cast<const f32x4*>(bias + vq * 4);
    f32x4 pfv[4], pgv[8];
#pragma unroll
    for (int t2 = 0; t2 < 4; ++t2) {
        f32x4 s = *reinterpret_cast<const f32x4*>(&sred[0][t2][vq * 4]);
        s += *reinterpret_cast<const f32x4*>(&sred[1][t2][vq * 4]);
        s += *reinterpret_cast<const f32x4*>(&sred[2][t2][vq * 4]);
        s += *reinterpret_cast<const f32x4*>(&sred[3][t2][vq * 4]);
        pfv[t2] = s + bi;
    }
#pragma unroll
    for (int ui = 0; ui < 8; ++ui)
        pgv[ui] = *reinterpret_cast<const f32x4*>(Pg + (b * 64 + ui * 8 + ug) * 128 + vq * 4);

    float* ob = out + (size_t)(b * 256 + t0) * 8192;
#pragma unroll
    for (int t2 = 0; t2 < 4; ++t2)
#pragma unroll
        for (int ui = 0; ui < 8; ++ui)
            *reinterpret_cast<f32x4*>(ob + (t2 * 64 + ui * 8 + ug) * 128 + vq * 4)
                = pfv[t2] + pgv[ui];

    if (blk == 96 && tid < 8) out[lens_off + tid] = (float)f_lens[tid];
}

extern "C" void kernel_launch(void* const* d_in, const int* in_sizes, int n_in,
                              void* d_out, int out_size, void* d_ws, size_t ws_size,
                              hipStream_t stream) {
    const float* f      = (const float*)d_in[0];
    const int*   f_lens = (const int*)  d_in[1];
    const float* g      = (const float*)d_in[2];
    // d_in[3] = g_lens (unused by reference output)
    const float* W      = (const float*)d_in[4];
    const float* bias   = (const float*)d_in[5];
    float* out = (float*)d_out;

    float*    Pg    = (float*)d_ws;                            // 256 KB
    short*    Wt    = (short*)((char*)d_ws + 262144);          // 256 KB
    unsigned* flags = (unsigned*)((char*)d_ws + 524288);       // 96 uints

    mega<<<dim3(608), dim3(256), 0, stream>>>(f, g, W, bias, f_lens, out,
                                              Pg, Wt, flags, out_size - 8);
}

// Round 6
// 26.357 us; speedup vs baseline: 4.9080x; 4.9080x over previous
//
#include <hip/hip_runtime.h>
#include <hip/hip_bf16.h>

// T=256, B=8, H1=512, U=64, H2=512, V=128
//   P rows 0..2047:    pf[b,t,v] = f[t,b,:]·W[:512,v]   (r = b*256+t)
//   P rows 2048..2559: pg[b,u,v] = g[b,u,:]·W[512:,v]   (r = 2048+b*64+u)
//   out[b,t,u,v] = pf + pg + bias; f_lens tail (8 floats).
// R4/R5 lesson: in-kernel cross-block sync (agent fences) collapses write BW
// to ~0.5 TB/s (per-XCD L2 invalidates). Use kernel boundaries (~2us each).
// K1 gathers B straight from raw f32 W (L2-hot) -> no transpose kernel, no deps.

typedef float  f32x4 __attribute__((ext_vector_type(4)));
typedef short  bh8   __attribute__((ext_vector_type(8)));

__device__ __forceinline__ unsigned short f2bf(float x) {
    unsigned u = __float_as_uint(x);
    return (unsigned short)((u + 0x7FFFu + ((u >> 16) & 1u)) >> 16);
}

// ---------------- K1: P GEMM, 320 blocks x 8 rows, wave-split-K (4x128) -------------
__global__ __launch_bounds__(256) void proj3(const float* __restrict__ F,
                                             const float* __restrict__ G,
                                             const float* __restrict__ W,
                                             float* __restrict__ P) {
    __shared__ float sred[4][8][128];            // 16 KB

    const int tid = threadIdx.x;
    const int rows8 = blockIdx.x * 8;            // P row base
    const bool isF = rows8 < 2048;
    const int koff = isF ? 0 : 512;
    const int w = tid >> 6, lane = tid & 63, l15 = lane & 15, cc = lane >> 4;

    const int rr = rows8 + (l15 & 7);
    const float* arow = isF ? F + (((rr & 255) << 3) + (rr >> 8)) * 512   // f[t][b][:]
                            : G + (rr - 2048) * 512;                      // g[b*64+u][:]

    f32x4 acc[8] = {};
#pragma unroll
    for (int kk = 0; kk < 4; ++kk) {
        const int k0 = w * 128 + kk * 32 + cc * 8;
        f32x4 a0 = *reinterpret_cast<const f32x4*>(arow + k0);
        f32x4 a1 = *reinterpret_cast<const f32x4*>(arow + k0 + 4);
        bh8 av;
        av[0] = (short)f2bf(a0[0]); av[1] = (short)f2bf(a0[1]);
        av[2] = (short)f2bf(a0[2]); av[3] = (short)f2bf(a0[3]);
        av[4] = (short)f2bf(a1[0]); av[5] = (short)f2bf(a1[1]);
        av[6] = (short)f2bf(a1[2]); av[7] = (short)f2bf(a1[3]);
#pragma unroll
        for (int j = 0; j < 8; ++j) {
            const float* wsrc = W + (koff + k0) * 128 + (j * 16 + l15);
            bh8 bv;
#pragma unroll
            for (int i = 0; i < 8; ++i) bv[i] = (short)f2bf(wsrc[i * 128]);
            acc[j] = __builtin_amdgcn_mfma_f32_16x16x32_bf16(av, bv, acc[j], 0, 0, 0);
        }
    }
    if (cc < 2) {                                // D rows m = cc*4+q in [0,8); m>=8 dup
#pragma unroll
        for (int j = 0; j < 8; ++j)
#pragma unroll
            for (int q = 0; q < 4; ++q)
                sred[w][cc * 4 + q][j * 16 + l15] = acc[j][q];
    }
    __syncthreads();

    const int row = tid >> 5, colq = tid & 31;
    f32x4 s = *reinterpret_cast<const f32x4*>(&sred[0][row][colq * 4]);
    s += *reinterpret_cast<const f32x4*>(&sred[1][row][colq * 4]);
    s += *reinterpret_cast<const f32x4*>(&sred[2][row][colq * 4]);
    s += *reinterpret_cast<const f32x4*>(&sred[3][row][colq * 4]);
    *reinterpret_cast<f32x4*>(P + (rows8 + row) * 128 + colq * 4) = s;
}

// ---------------- K2: broadcast add + stream out + lens tail ------------------------
__global__ __launch_bounds__(256) void bcast(const float* __restrict__ P,
                                             const float* __restrict__ bias,
                                             const int* __restrict__ f_lens,
                                             float* __restrict__ out,
                                             int lens_off) {
    const int r   = blockIdx.x;        // b*256 + t
    const int tid = threadIdx.x;
    const int b   = r >> 8;
    const int vq  = tid & 31;          // float4 index in V
    const int u0  = tid >> 5;          // 0..7

    f32x4 pf = *reinterpret_cast<const f32x4*>(P + r * 128 + vq * 4);
    f32x4 bi = *reinterpret_cast<const f32x4*>(bias + vq * 4);
    pf += bi;

    const float* pg = P + (2048 + b * 64) * 128;
    float* ob = out + (size_t)r * 8192;

#pragma unroll
    for (int i = 0; i < 8; ++i) {
        int u = u0 * 8 + i;
        f32x4 v = *reinterpret_cast<const f32x4*>(pg + u * 128 + vq * 4);
        v += pf;
        *reinterpret_cast<f32x4*>(ob + u * 128 + vq * 4) = v;
    }

    if (r == 0 && tid < 8) out[lens_off + tid] = (float)f_lens[tid];
}

extern "C" void kernel_launch(void* const* d_in, const int* in_sizes, int n_in,
                              void* d_out, int out_size, void* d_ws, size_t ws_size,
                              hipStream_t stream) {
    const float* f      = (const float*)d_in[0];
    const int*   f_lens = (const int*)  d_in[1];
    const float* g      = (const float*)d_in[2];
    // d_in[3] = g_lens (unused by reference output)
    const float* W      = (const float*)d_in[4];
    const float* bias   = (const float*)d_in[5];
    float* out = (float*)d_out;

    float* P = (float*)d_ws;                                   // 2560*128*4 = 1.25 MB

    proj3<<<dim3(320),  dim3(256), 0, stream>>>(f, g, W, P);
    bcast<<<dim3(2048), dim3(256), 0, stream>>>(P, bias, f_lens, out, out_size - 8);
}